// Round 6
// baseline (282.285 us; speedup 1.0000x reference)
//
#include <hip/hip_runtime.h>
#include <hip/hip_bf16.h>

// ---------------------------------------------------------------------------
// GraphSAGE 3-layer forward. bf16 MFMA GEMMs (f32 accum), bf16 activations.
// R6: register-only GEMMs — no LDS, no barriers. Each wave owns a 16-row
// strip; A-fragments loaded global->VGPR, B-fragments read from the 32KB
// L2-hot transposed weight table. 3125 independent waves per GEMM.
//   layer0: H = relu(x@Wr0 + segmean(x)@Wl0 + b0)
//   layer1: P(bf16) = H@Wr1 + segmean(H)@Wl1 + b1 (+f32 BN stats);
//           H = bf16(relu(BN(P)) + x)
//   layer2: A64=H@Wl2; B64=segmean(A64); out = log_softmax(H@Wr2 + B64 + b2)
// ---------------------------------------------------------------------------

#define WS_EPS 1e-5f

typedef unsigned short ushort_t;
typedef unsigned int uint_t;
typedef ushort_t ushort8 __attribute__((ext_vector_type(8)));
typedef short short8 __attribute__((ext_vector_type(8)));
typedef float f32x4 __attribute__((ext_vector_type(4)));

__device__ __forceinline__ float bf2f(ushort_t u) {
    return __uint_as_float(((uint_t)u) << 16);
}
__device__ __forceinline__ ushort_t f2bf(float f) {
    uint_t u = __float_as_uint(f);
    u = (u + 0x7fffu + ((u >> 16) & 1u)) >> 16;  // RNE
    return (ushort_t)u;
}

// ---- CSR build -------------------------------------------------------------
__global__ __launch_bounds__(256) void k_deg(const int* __restrict__ ei,
                                             int* __restrict__ deg, int E) {
    int e = blockIdx.x * 256 + threadIdx.x;
    if (e < E) atomicAdd(&deg[ei[E + e]], 1);
}

constexpr int SCHUNK = 4096;

__global__ __launch_bounds__(256) void k_scan_part(const int* __restrict__ deg,
                                                   int* __restrict__ bsum, int n) {
    int t = threadIdx.x;
    int base = blockIdx.x * SCHUNK + t * 16;
    int s = 0;
#pragma unroll
    for (int j = 0; j < 16; ++j) {
        int i = base + j;
        if (i < n) s += deg[i];
    }
#pragma unroll
    for (int d = 1; d < 64; d <<= 1) s += __shfl_xor(s, d);
    __shared__ int wt[4];
    if ((t & 63) == 0) wt[t >> 6] = s;
    __syncthreads();
    if (t == 0) bsum[blockIdx.x] = wt[0] + wt[1] + wt[2] + wt[3];
}

__global__ __launch_bounds__(64) void k_scan_bsum(const int* __restrict__ bsum,
                                                  int* __restrict__ boff,
                                                  int* __restrict__ off_n, int nb) {
    int lane = threadIdx.x;
    int carry = 0;
    for (int base = 0; base < nb; base += 64) {
        int t = base + lane;
        int v = (t < nb) ? bsum[t] : 0;
        int x = v;
#pragma unroll
        for (int d = 1; d < 64; d <<= 1) {
            int y = __shfl_up(x, d);
            if (lane >= d) x += y;
        }
        if (t < nb) boff[t] = carry + x - v;
        carry += __shfl(x, 63);
    }
    if (lane == 0) *off_n = carry;
}

__global__ __launch_bounds__(256) void k_scan_apply(const int* __restrict__ deg,
                                                    const int* __restrict__ boff,
                                                    int* __restrict__ off, int n) {
    int t = threadIdx.x;
    int lane = t & 63, wid = t >> 6;
    int base = blockIdx.x * SCHUNK + t * 16;
    int v[16];
    int s = 0;
#pragma unroll
    for (int j = 0; j < 16; ++j) {
        int i = base + j;
        v[j] = (i < n) ? deg[i] : 0;
        s += v[j];
    }
    int x = s;
#pragma unroll
    for (int d = 1; d < 64; d <<= 1) {
        int y = __shfl_up(x, d);
        if (lane >= d) x += y;
    }
    __shared__ int wtot[4];
    if (lane == 63) wtot[wid] = x;
    __syncthreads();
    int woff = 0;
    for (int wj = 0; wj < wid; ++wj) woff += wtot[wj];
    int run = boff[blockIdx.x] + woff + x - s;
#pragma unroll
    for (int j = 0; j < 16; ++j) {
        int i = base + j;
        if (i < n) off[i] = run;
        run += v[j];
    }
}

__global__ __launch_bounds__(256) void k_scatter(const int* __restrict__ ei,
                                                 const int* __restrict__ off,
                                                 int* __restrict__ cur,
                                                 int* __restrict__ csr, int E) {
    int e = blockIdx.x * 256 + threadIdx.x;
    if (e < E) {
        int d = ei[E + e];
        int s = ei[e];
        int p = atomicAdd(&cur[d], 1);
        csr[off[d] + p] = s;
    }
}

// ---- prep: x -> bf16 AND weights -> bf16 transposed, one launch -------------
__global__ __launch_bounds__(256) void k_prep(const float* __restrict__ x,
                                              ushort_t* __restrict__ xb, int total2,
                                              int nb_cvt,
                                              const float* __restrict__ Wl0,
                                              const float* __restrict__ Wr0,
                                              const float* __restrict__ Wl1,
                                              const float* __restrict__ Wr1,
                                              const float* __restrict__ Wl2,
                                              const float* __restrict__ Wr2,
                                              ushort_t* __restrict__ wts) {
    int b = blockIdx.x;
    if (b < nb_cvt) {
        int i = b * 256 + threadIdx.x;
        if (i >= total2) return;
        float2 v = *(const float2*)&x[(size_t)i * 2];
        uint_t p = (uint_t)f2bf(v.x) | ((uint_t)f2bf(v.y) << 16);
        *(uint_t*)&xb[(size_t)i * 2] = p;
        return;
    }
    int id = (b - nb_cvt) * 256 + threadIdx.x;
    if (id >= 81920) return;
    const float* W;
    int rel, nout, base;
    if (id < 65536) {
        int m = id >> 14;
        rel = id & 16383;
        nout = 128;
        base = m << 14;
        W = (m == 0) ? Wl0 : (m == 1) ? Wr0 : (m == 2) ? Wl1 : Wr1;
    } else {
        int m = (id - 65536) >> 13;
        rel = (id - 65536) & 8191;
        nout = 64;
        base = 65536 + (m << 13);
        W = (m == 0) ? Wl2 : Wr2;
    }
    int c = rel >> 7;
    int k = rel & 127;
    wts[base + rel] = f2bf(W[(size_t)k * nout + c]);
}

// ---- register-only MFMA GEMM, one 16-row strip per wave, no LDS/barriers ---
// out[n][NOUT] = X1@W1 (+ X2@W2) + bias, K=128. WT layout: [col][k].
// EPI: 2 -> dual-phase, relu, bf16 out (layer 0)
//      1 -> dual-phase, bf16 out + f32 BN stats atomics (layer 1)
//      0 -> single-phase, bf16 out, no bias (layer 2 Wl pass)
//      3 -> single-phase, +AGG+bias, fused row log_softmax, f32 out (final)
template <int NOUT, int EPI>
__global__ __launch_bounds__(256, 2) void k_rgemm(const ushort_t* __restrict__ X1,
                                                  const ushort_t* __restrict__ W1,
                                                  const ushort_t* __restrict__ X2,
                                                  const ushort_t* __restrict__ W2,
                                                  const ushort_t* __restrict__ AGG,
                                                  const float* __restrict__ bias,
                                                  void* __restrict__ outv,
                                                  float* __restrict__ stats, int n) {
    constexpr int K = 128;
    constexpr int FN = NOUT / 16;  // 8 or 4
    constexpr bool DUAL = (EPI == 1 || EPI == 2);

    const int t = threadIdx.x;
    const int lane = t & 63;
    const int r16 = lane & 15, kb = lane >> 4;
    const int wv = blockIdx.x * 4 + (t >> 6);
    const int base = wv * 16;
    const int arow = base + r16;
    const bool rok = (arow < n);
    const size_t xoff = (size_t)arow * K + kb * 8;

    f32x4 acc[FN];
#pragma unroll
    for (int j = 0; j < FN; ++j) acc[j] = (f32x4)0.f;

    // phase 0
    {
        short8 a[4];
#pragma unroll
        for (int ks = 0; ks < 4; ++ks)
            a[ks] = rok ? *(const short8*)&X1[xoff + ks * 32] : (short8)0;
#pragma unroll
        for (int ks = 0; ks < 4; ++ks) {
#pragma unroll
            for (int fn = 0; fn < FN; ++fn) {
                short8 b = *(const short8*)&W1[(size_t)(fn * 16 + r16) * K + ks * 32 + kb * 8];
                acc[fn] = __builtin_amdgcn_mfma_f32_16x16x32_bf16(a[ks], b, acc[fn], 0, 0, 0);
            }
        }
    }
    if constexpr (DUAL) {
        short8 a[4];
#pragma unroll
        for (int ks = 0; ks < 4; ++ks)
            a[ks] = rok ? *(const short8*)&X2[xoff + ks * 32] : (short8)0;
#pragma unroll
        for (int ks = 0; ks < 4; ++ks) {
#pragma unroll
            for (int fn = 0; fn < FN; ++fn) {
                short8 b = *(const short8*)&W2[(size_t)(fn * 16 + r16) * K + ks * 32 + kb * 8];
                acc[fn] = __builtin_amdgcn_mfma_f32_16x16x32_bf16(a[ks], b, acc[fn], 0, 0, 0);
            }
        }
    }

    if constexpr (EPI == 2) {
#pragma unroll
        for (int r = 0; r < 4; ++r) {
            int row = base + kb * 4 + r;
            if (row >= n) continue;
#pragma unroll
            for (int fn = 0; fn < FN; ++fn) {
                int col = fn * 16 + r16;
                float v = acc[fn][r] + bias[col];
                ((ushort_t*)outv)[(size_t)row * NOUT + col] = f2bf(fmaxf(v, 0.f));
            }
        }
    } else if constexpr (EPI == 1) {
        float s[FN], q[FN];
#pragma unroll
        for (int fn = 0; fn < FN; ++fn) { s[fn] = 0.f; q[fn] = 0.f; }
#pragma unroll
        for (int r = 0; r < 4; ++r) {
            int row = base + kb * 4 + r;
            if (row >= n) continue;
#pragma unroll
            for (int fn = 0; fn < FN; ++fn) {
                int col = fn * 16 + r16;
                float v = acc[fn][r] + bias[col];
                ((ushort_t*)outv)[(size_t)row * NOUT + col] = f2bf(v);
                s[fn] += v;
                q[fn] += v * v;
            }
        }
        // reduce over the 4 kb-groups (same col set), then block, then global
#pragma unroll
        for (int fn = 0; fn < FN; ++fn) {
            s[fn] += __shfl_xor(s[fn], 16);
            s[fn] += __shfl_xor(s[fn], 32);
            q[fn] += __shfl_xor(q[fn], 16);
            q[fn] += __shfl_xor(q[fn], 32);
        }
        __shared__ float sred[256];
        sred[t] = 0.f;
        __syncthreads();
        if (kb == 0) {
#pragma unroll
            for (int fn = 0; fn < FN; ++fn) {
                int col = fn * 16 + r16;
                atomicAdd(&sred[col], s[fn]);
                atomicAdd(&sred[128 + col], q[fn]);
            }
        }
        __syncthreads();
        atomicAdd(&stats[t], sred[t]);
    } else if constexpr (EPI == 0) {
#pragma unroll
        for (int r = 0; r < 4; ++r) {
            int row = base + kb * 4 + r;
            if (row >= n) continue;
#pragma unroll
            for (int fn = 0; fn < FN; ++fn) {
                int col = fn * 16 + r16;
                ((ushort_t*)outv)[(size_t)row * NOUT + col] = f2bf(acc[fn][r]);
            }
        }
    } else {  // EPI == 3: +AGG+bias, row log_softmax (NOUT==64)
        float* outp = (float*)outv;
#pragma unroll
        for (int r = 0; r < 4; ++r) {
            int row = base + kb * 4 + r;
            bool ok = (row < n);
            float vv[FN];
#pragma unroll
            for (int fn = 0; fn < FN; ++fn) {
                int col = fn * 16 + r16;
                vv[fn] = ok ? (acc[fn][r] + bf2f(AGG[(size_t)row * NOUT + col]) + bias[col])
                            : 0.f;
            }
            float m = fmaxf(fmaxf(vv[0], vv[1]), fmaxf(vv[2], vv[3]));
#pragma unroll
            for (int d = 1; d < 16; d <<= 1) m = fmaxf(m, __shfl_xor(m, d));
            float e = expf(vv[0] - m) + expf(vv[1] - m) + expf(vv[2] - m) + expf(vv[3] - m);
#pragma unroll
            for (int d = 1; d < 16; d <<= 1) e += __shfl_xor(e, d);
            float lg = m + logf(e);
            if (ok) {
#pragma unroll
                for (int fn = 0; fn < FN; ++fn)
                    outp[(size_t)row * NOUT + fn * 16 + r16] = vv[fn] - lg;
            }
        }
    }
}

// ---- segment mean over CSR: 16 lanes/node (D=128) or 8 (D=64), 16B loads ---
template <int D>
__global__ __launch_bounds__(256) void k_segmean_bf(const ushort_t* __restrict__ U,
                                                    const int* __restrict__ off,
                                                    const int* __restrict__ srcs,
                                                    ushort_t* __restrict__ out,
                                                    int n) {
    constexpr int L = D / 8;       // lanes per node: 16 or 8
    constexpr int PER = 256 / L;   // nodes per block
    int node = blockIdx.x * PER + threadIdx.x / L;
    int sub = threadIdx.x % L;
    if (node >= n) return;
    int beg = off[node], end = off[node + 1];
    float a[8];
#pragma unroll
    for (int j = 0; j < 8; ++j) a[j] = 0.f;
    int i = beg;
    for (; i + 8 <= end; i += 8) {
        int sv[8];
#pragma unroll
        for (int u = 0; u < 8; ++u) sv[u] = srcs[i + u];
#pragma unroll
        for (int u = 0; u < 8; ++u) {
            ushort8 v = *(const ushort8*)&U[(size_t)sv[u] * D + sub * 8];
#pragma unroll
            for (int j = 0; j < 8; ++j) a[j] += bf2f((ushort_t)v[j]);
        }
    }
    for (; i + 4 <= end; i += 4) {
        int sv[4];
#pragma unroll
        for (int u = 0; u < 4; ++u) sv[u] = srcs[i + u];
#pragma unroll
        for (int u = 0; u < 4; ++u) {
            ushort8 v = *(const ushort8*)&U[(size_t)sv[u] * D + sub * 8];
#pragma unroll
            for (int j = 0; j < 8; ++j) a[j] += bf2f((ushort_t)v[j]);
        }
    }
    for (; i < end; ++i) {
        ushort8 v = *(const ushort8*)&U[(size_t)srcs[i] * D + sub * 8];
#pragma unroll
        for (int j = 0; j < 8; ++j) a[j] += bf2f((ushort_t)v[j]);
    }
    int d = end - beg;
    float inv = 1.f / (float)(d > 1 ? d : 1);
    ushort8 o;
#pragma unroll
    for (int j = 0; j < 8; ++j) o[j] = f2bf(a[j] * inv);
    *(ushort8*)&out[(size_t)node * D + sub * 8] = o;
}

// ---- BN apply + relu + residual(x f32), P bf16 -> H bf16 -------------------
__global__ __launch_bounds__(256) void k_bnapply(const ushort_t* __restrict__ P,
                                                 const float* __restrict__ X,
                                                 const float* __restrict__ stats,
                                                 const float* __restrict__ gamma,
                                                 const float* __restrict__ beta,
                                                 ushort_t* __restrict__ H, int n) {
    int i = blockIdx.x * 256 + threadIdx.x;  // one thread = 2 channels
    if (i >= n * 64) return;
    int nd = i >> 6;
    int c = (i & 63) << 1;
    float inv_n = 1.f / (float)n;
    float mu0 = stats[c] * inv_n, mu1 = stats[c + 1] * inv_n;
    float v0 = stats[128 + c] * inv_n - mu0 * mu0;
    float v1 = stats[128 + c + 1] * inv_n - mu1 * mu1;
    float s0 = rsqrtf(v0 + WS_EPS) * gamma[c];
    float s1 = rsqrtf(v1 + WS_EPS) * gamma[c + 1];
    uint_t pv = *(const uint_t*)&P[(size_t)nd * 128 + c];
    float p0 = __uint_as_float(pv << 16);
    float p1 = __uint_as_float(pv & 0xffff0000u);
    float2 xr = *(const float2*)&X[(size_t)nd * 128 + c];
    float h0 = fmaxf((p0 - mu0) * s0 + beta[c], 0.f) + xr.x;
    float h1 = fmaxf((p1 - mu1) * s1 + beta[c + 1], 0.f) + xr.y;
    uint_t pk = (uint_t)f2bf(h0) | ((uint_t)f2bf(h1) << 16);
    *(uint_t*)&H[(size_t)nd * 128 + c] = pk;
}

// ---------------------------------------------------------------------------
extern "C" void kernel_launch(void* const* d_in, const int* in_sizes, int n_in,
                              void* d_out, int out_size, void* d_ws, size_t ws_size,
                              hipStream_t stream) {
    const float* x     = (const float*)d_in[0];
    const int*   ei    = (const int*)d_in[1];
    const float* Wl0   = (const float*)d_in[2];
    const float* Wr0   = (const float*)d_in[3];
    const float* b0    = (const float*)d_in[4];
    const float* Wl1   = (const float*)d_in[5];
    const float* Wr1   = (const float*)d_in[6];
    const float* b1    = (const float*)d_in[7];
    const float* Wl2   = (const float*)d_in[8];
    const float* Wr2   = (const float*)d_in[9];
    const float* b2    = (const float*)d_in[10];
    const float* gamma = (const float*)d_in[11];
    const float* beta  = (const float*)d_in[12];

    const int n = in_sizes[0] / 128;
    const int E = in_sizes[1] / 2;
    const int nb_scan = (n + SCHUNK - 1) / SCHUNK;

    char* w = (char*)d_ws;
    auto alloc = [&](size_t bytes) -> void* {
        void* p = (void*)w;
        w += (bytes + 255) & ~(size_t)255;
        return p;
    };
    int*      deg   = (int*)alloc((size_t)n * 4);
    int*      cur   = (int*)alloc((size_t)n * 4);
    float*    stats = (float*)alloc(256 * 4);
    size_t    zbytes = (size_t)((char*)w - (char*)deg);
    int*      off   = (int*)alloc(((size_t)n + 1) * 4);
    int*      csr   = (int*)alloc((size_t)E * 4);
    int*      bsum  = (int*)alloc(256 * 4);
    int*      boff  = (int*)alloc(256 * 4);
    ushort_t* wts   = (ushort_t*)alloc((size_t)81920 * 2);
    ushort_t* xb    = (ushort_t*)alloc((size_t)n * 128 * 2);
    ushort_t* H     = (ushort_t*)alloc((size_t)n * 128 * 2);
    ushort_t* Pb    = (ushort_t*)alloc((size_t)n * 128 * 2);
    ushort_t* slabB = (ushort_t*)alloc((size_t)n * 128 * 2);

    ushort_t* WtL0 = wts;
    ushort_t* WtR0 = wts + 16384;
    ushort_t* WtL1 = wts + 32768;
    ushort_t* WtR1 = wts + 49152;
    ushort_t* WtL2 = wts + 65536;
    ushort_t* WtR2 = wts + 73728;

    ushort_t* M   = slabB;
    ushort_t* A64 = slabB;
    ushort_t* B64 = slabB + (size_t)n * 64;

    hipMemsetAsync(deg, 0, zbytes, stream);

    const int eb = (E + 255) / 256;
    k_deg<<<eb, 256, 0, stream>>>(ei, deg, E);
    k_scan_part<<<nb_scan, 256, 0, stream>>>(deg, bsum, n);
    k_scan_bsum<<<1, 64, 0, stream>>>(bsum, boff, off + n, nb_scan);
    k_scan_apply<<<nb_scan, 256, 0, stream>>>(deg, boff, off, n);
    k_scatter<<<eb, 256, 0, stream>>>(ei, off, cur, csr, E);

    const int nb_cvt = (n * 64 + 255) / 256;
    k_prep<<<nb_cvt + 320, 256, 0, stream>>>(x, xb, n * 64, nb_cvt,
                                             Wl0, Wr0, Wl1, Wr1, Wl2, Wr2, wts);

    const int gb = (n / 16 + 3) / 4;          // 4 waves/block, 16 rows/wave
    const int smb128 = (n + 15) / 16;
    const int smb64 = (n + 31) / 32;

    // layer 0: M = segmean(xb); H = relu(xb@Wr0 + M@Wl0 + b0)
    k_segmean_bf<128><<<smb128, 256, 0, stream>>>(xb, off, csr, M, n);
    k_rgemm<128, 2><<<gb, 256, 0, stream>>>(xb, WtR0, M, WtL0, nullptr, b0, H, nullptr, n);

    // layer 1: M = segmean(H); Pb = H@Wr1 + M@Wl1 + b1 (+BN stats);
    //          H = bf16(relu(BN(Pb)) + x)
    k_segmean_bf<128><<<smb128, 256, 0, stream>>>(H, off, csr, M, n);
    k_rgemm<128, 1><<<gb, 256, 0, stream>>>(H, WtR1, M, WtL1, nullptr, b1, Pb, stats, n);
    k_bnapply<<<(n * 64 + 255) / 256, 256, 0, stream>>>(Pb, x, stats, gamma, beta, H, n);

    // layer 2 (commuted; log_softmax fused into final GEMM epilogue)
    k_rgemm<64, 0><<<gb, 256, 0, stream>>>(H, WtL2, nullptr, nullptr, nullptr, nullptr, A64, nullptr, n);
    k_segmean_bf<64><<<smb64, 256, 0, stream>>>(A64, off, csr, B64, n);
    k_rgemm<64, 3><<<gb, 256, 0, stream>>>(H, WtR2, nullptr, nullptr, B64, b2, (float*)d_out, nullptr, n);
}

// Round 7
// 282.272 us; speedup vs baseline: 1.0000x; 1.0000x over previous
//
#include <hip/hip_runtime.h>
#include <hip/hip_bf16.h>

// ---------------------------------------------------------------------------
// GraphSAGE 3-layer forward. bf16 MFMA GEMMs (f32 accum), bf16 activations.
// R7: Little's-law fix — GEMM waves col-split to 16rows x 64cols (6250 waves,
// 2x occupancy, half per-wave chain), all A-fragments issued before MFMAs,
// no LDS/barriers. Layer-2's two H-GEMMs merged into one kernel (A64 and T),
// final log_softmax is a separate cheap elementwise kernel.
//   layer0: H = relu(x@Wr0 + segmean(x)@Wl0 + b0)
//   layer1: Pb = H@Wr1 + segmean(H)@Wl1 + b1 (+f32 BN stats);
//           H = bf16(relu(BN(Pb)) + x)
//   layer2: {A64 = H@Wl2, T = H@Wr2 + b2}; B64 = segmean(A64);
//           out = log_softmax(T + B64)
// ---------------------------------------------------------------------------

#define WS_EPS 1e-5f

typedef unsigned short ushort_t;
typedef unsigned int uint_t;
typedef ushort_t ushort8 __attribute__((ext_vector_type(8)));
typedef ushort_t ushort4v __attribute__((ext_vector_type(4)));
typedef short short8 __attribute__((ext_vector_type(8)));
typedef float f32x4 __attribute__((ext_vector_type(4)));

__device__ __forceinline__ float bf2f(ushort_t u) {
    return __uint_as_float(((uint_t)u) << 16);
}
__device__ __forceinline__ ushort_t f2bf(float f) {
    uint_t u = __float_as_uint(f);
    u = (u + 0x7fffu + ((u >> 16) & 1u)) >> 16;  // RNE
    return (ushort_t)u;
}

// ---- CSR build -------------------------------------------------------------
__global__ __launch_bounds__(256) void k_deg(const int* __restrict__ ei,
                                             int* __restrict__ deg, int E) {
    int e = blockIdx.x * 256 + threadIdx.x;
    if (e < E) atomicAdd(&deg[ei[E + e]], 1);
}

constexpr int SCHUNK = 4096;

__global__ __launch_bounds__(256) void k_scan_part(const int* __restrict__ deg,
                                                   int* __restrict__ bsum, int n) {
    int t = threadIdx.x;
    int base = blockIdx.x * SCHUNK + t * 16;
    int s = 0;
#pragma unroll
    for (int j = 0; j < 16; ++j) {
        int i = base + j;
        if (i < n) s += deg[i];
    }
#pragma unroll
    for (int d = 1; d < 64; d <<= 1) s += __shfl_xor(s, d);
    __shared__ int wt[4];
    if ((t & 63) == 0) wt[t >> 6] = s;
    __syncthreads();
    if (t == 0) bsum[blockIdx.x] = wt[0] + wt[1] + wt[2] + wt[3];
}

__global__ __launch_bounds__(64) void k_scan_bsum(const int* __restrict__ bsum,
                                                  int* __restrict__ boff,
                                                  int* __restrict__ off_n, int nb) {
    int lane = threadIdx.x;
    int carry = 0;
    for (int base = 0; base < nb; base += 64) {
        int t = base + lane;
        int v = (t < nb) ? bsum[t] : 0;
        int x = v;
#pragma unroll
        for (int d = 1; d < 64; d <<= 1) {
            int y = __shfl_up(x, d);
            if (lane >= d) x += y;
        }
        if (t < nb) boff[t] = carry + x - v;
        carry += __shfl(x, 63);
    }
    if (lane == 0) *off_n = carry;
}

__global__ __launch_bounds__(256) void k_scan_apply(const int* __restrict__ deg,
                                                    const int* __restrict__ boff,
                                                    int* __restrict__ off, int n) {
    int t = threadIdx.x;
    int lane = t & 63, wid = t >> 6;
    int base = blockIdx.x * SCHUNK + t * 16;
    int v[16];
    int s = 0;
#pragma unroll
    for (int j = 0; j < 16; ++j) {
        int i = base + j;
        v[j] = (i < n) ? deg[i] : 0;
        s += v[j];
    }
    int x = s;
#pragma unroll
    for (int d = 1; d < 64; d <<= 1) {
        int y = __shfl_up(x, d);
        if (lane >= d) x += y;
    }
    __shared__ int wtot[4];
    if (lane == 63) wtot[wid] = x;
    __syncthreads();
    int woff = 0;
    for (int wj = 0; wj < wid; ++wj) woff += wtot[wj];
    int run = boff[blockIdx.x] + woff + x - s;
#pragma unroll
    for (int j = 0; j < 16; ++j) {
        int i = base + j;
        if (i < n) off[i] = run;
        run += v[j];
    }
}

__global__ __launch_bounds__(256) void k_scatter(const int* __restrict__ ei,
                                                 const int* __restrict__ off,
                                                 int* __restrict__ cur,
                                                 int* __restrict__ csr, int E) {
    int e = blockIdx.x * 256 + threadIdx.x;
    if (e < E) {
        int d = ei[E + e];
        int s = ei[e];
        int p = atomicAdd(&cur[d], 1);
        csr[off[d] + p] = s;
    }
}

// ---- prep: x -> bf16 AND weights -> bf16 transposed, one launch -------------
__global__ __launch_bounds__(256) void k_prep(const float* __restrict__ x,
                                              ushort_t* __restrict__ xb, int total2,
                                              int nb_cvt,
                                              const float* __restrict__ Wl0,
                                              const float* __restrict__ Wr0,
                                              const float* __restrict__ Wl1,
                                              const float* __restrict__ Wr1,
                                              const float* __restrict__ Wl2,
                                              const float* __restrict__ Wr2,
                                              ushort_t* __restrict__ wts) {
    int b = blockIdx.x;
    if (b < nb_cvt) {
        int i = b * 256 + threadIdx.x;
        if (i >= total2) return;
        float2 v = *(const float2*)&x[(size_t)i * 2];
        uint_t p = (uint_t)f2bf(v.x) | ((uint_t)f2bf(v.y) << 16);
        *(uint_t*)&xb[(size_t)i * 2] = p;
        return;
    }
    int id = (b - nb_cvt) * 256 + threadIdx.x;
    if (id >= 81920) return;
    const float* W;
    int rel, nout, base;
    if (id < 65536) {
        int m = id >> 14;
        rel = id & 16383;
        nout = 128;
        base = m << 14;
        W = (m == 0) ? Wl0 : (m == 1) ? Wr0 : (m == 2) ? Wl1 : Wr1;
    } else {
        int m = (id - 65536) >> 13;
        rel = (id - 65536) & 8191;
        nout = 64;
        base = 65536 + (m << 13);
        W = (m == 0) ? Wl2 : Wr2;
    }
    int c = rel >> 7;
    int k = rel & 127;
    wts[base + rel] = f2bf(W[(size_t)k * nout + c]);
}

// ---- dual-phase GEMM, col-split: wave = 16 rows x 64 cols, K=128 x 2 -------
// out[n][128] = X1@W1 + X2@W2 + bias. WT layout [col][k]. No LDS in main path.
// EPI: 2 -> relu, bf16 out (layer 0); 1 -> bf16 out + f32 BN stats (layer 1).
template <int EPI>
__global__ __launch_bounds__(256) void k_dgemm(const ushort_t* __restrict__ X1,
                                               const ushort_t* __restrict__ W1,
                                               const ushort_t* __restrict__ X2,
                                               const ushort_t* __restrict__ W2,
                                               const float* __restrict__ bias,
                                               ushort_t* __restrict__ outp,
                                               float* __restrict__ stats, int n) {
    constexpr int K = 128, NOUT = 128, FN = 4;
    const int t = threadIdx.x;
    const int lane = t & 63;
    const int r16 = lane & 15, kb = lane >> 4;
    const int gwv = blockIdx.x * 4 + (t >> 6);
    const int strip = gwv >> 1;
    const int col0 = (gwv & 1) * 64;
    const int base = strip * 16;
    const int arow = base + r16;
    const bool rok = (arow < n);
    const size_t xoff = (size_t)arow * K + kb * 8;

    // issue ALL A-loads (both phases) before any MFMA
    short8 a1[4], a2[4];
#pragma unroll
    for (int ks = 0; ks < 4; ++ks)
        a1[ks] = rok ? *(const short8*)&X1[xoff + ks * 32] : (short8)0;
#pragma unroll
    for (int ks = 0; ks < 4; ++ks)
        a2[ks] = rok ? *(const short8*)&X2[xoff + ks * 32] : (short8)0;

    f32x4 acc[FN];
#pragma unroll
    for (int j = 0; j < FN; ++j) acc[j] = (f32x4)0.f;

#pragma unroll
    for (int ks = 0; ks < 4; ++ks) {
#pragma unroll
        for (int fn = 0; fn < FN; ++fn) {
            short8 b = *(const short8*)&W1[(size_t)(col0 + fn * 16 + r16) * K + ks * 32 + kb * 8];
            acc[fn] = __builtin_amdgcn_mfma_f32_16x16x32_bf16(a1[ks], b, acc[fn], 0, 0, 0);
        }
    }
#pragma unroll
    for (int ks = 0; ks < 4; ++ks) {
#pragma unroll
        for (int fn = 0; fn < FN; ++fn) {
            short8 b = *(const short8*)&W2[(size_t)(col0 + fn * 16 + r16) * K + ks * 32 + kb * 8];
            acc[fn] = __builtin_amdgcn_mfma_f32_16x16x32_bf16(a2[ks], b, acc[fn], 0, 0, 0);
        }
    }

    if constexpr (EPI == 2) {
#pragma unroll
        for (int r = 0; r < 4; ++r) {
            int row = base + kb * 4 + r;
            if (row >= n) continue;
#pragma unroll
            for (int fn = 0; fn < FN; ++fn) {
                int col = col0 + fn * 16 + r16;
                float v = acc[fn][r] + bias[col];
                outp[(size_t)row * NOUT + col] = f2bf(fmaxf(v, 0.f));
            }
        }
    } else {
        float s[FN], q[FN];
#pragma unroll
        for (int fn = 0; fn < FN; ++fn) { s[fn] = 0.f; q[fn] = 0.f; }
#pragma unroll
        for (int r = 0; r < 4; ++r) {
            int row = base + kb * 4 + r;
            if (row >= n) continue;
#pragma unroll
            for (int fn = 0; fn < FN; ++fn) {
                int col = col0 + fn * 16 + r16;
                float v = acc[fn][r] + bias[col];
                outp[(size_t)row * NOUT + col] = f2bf(v);
                s[fn] += v;
                q[fn] += v * v;
            }
        }
#pragma unroll
        for (int fn = 0; fn < FN; ++fn) {
            s[fn] += __shfl_xor(s[fn], 16);
            s[fn] += __shfl_xor(s[fn], 32);
            q[fn] += __shfl_xor(q[fn], 16);
            q[fn] += __shfl_xor(q[fn], 32);
        }
        __shared__ float sred[256];
        sred[t] = 0.f;
        __syncthreads();
        if (kb == 0) {
#pragma unroll
            for (int fn = 0; fn < FN; ++fn) {
                int col = col0 + fn * 16 + r16;
                atomicAdd(&sred[col], s[fn]);
                atomicAdd(&sred[128 + col], q[fn]);
            }
        }
        __syncthreads();
        atomicAdd(&stats[t], sred[t]);
    }
}

// ---- layer-2 combined GEMM: A64 = H@Wl2 (bf16), T = H@Wr2 + b2 (f32) -------
// wave = 16 rows x one 64-col half (h=0 -> Wl2/A64, h=1 -> Wr2/T).
__global__ __launch_bounds__(256) void k_cgemm(const ushort_t* __restrict__ H,
                                               const ushort_t* __restrict__ WL,
                                               const ushort_t* __restrict__ WR,
                                               const float* __restrict__ b2,
                                               ushort_t* __restrict__ A64,
                                               float* __restrict__ T, int n) {
    constexpr int K = 128, FN = 4;
    const int t = threadIdx.x;
    const int lane = t & 63;
    const int r16 = lane & 15, kb = lane >> 4;
    const int gwv = blockIdx.x * 4 + (t >> 6);
    const int strip = gwv >> 1;
    const int h = gwv & 1;
    const int base = strip * 16;
    const int arow = base + r16;
    const bool rok = (arow < n);
    const size_t xoff = (size_t)arow * K + kb * 8;
    const ushort_t* W = h ? WR : WL;

    short8 a[4];
#pragma unroll
    for (int ks = 0; ks < 4; ++ks)
        a[ks] = rok ? *(const short8*)&H[xoff + ks * 32] : (short8)0;

    f32x4 acc[FN];
#pragma unroll
    for (int j = 0; j < FN; ++j) acc[j] = (f32x4)0.f;

#pragma unroll
    for (int ks = 0; ks < 4; ++ks) {
#pragma unroll
        for (int fn = 0; fn < FN; ++fn) {
            short8 b = *(const short8*)&W[(size_t)(fn * 16 + r16) * K + ks * 32 + kb * 8];
            acc[fn] = __builtin_amdgcn_mfma_f32_16x16x32_bf16(a[ks], b, acc[fn], 0, 0, 0);
        }
    }

    if (h == 0) {
#pragma unroll
        for (int r = 0; r < 4; ++r) {
            int row = base + kb * 4 + r;
            if (row >= n) continue;
#pragma unroll
            for (int fn = 0; fn < FN; ++fn)
                A64[(size_t)row * 64 + fn * 16 + r16] = f2bf(acc[fn][r]);
        }
    } else {
#pragma unroll
        for (int r = 0; r < 4; ++r) {
            int row = base + kb * 4 + r;
            if (row >= n) continue;
#pragma unroll
            for (int fn = 0; fn < FN; ++fn) {
                int col = fn * 16 + r16;
                T[(size_t)row * 64 + col] = acc[fn][r] + b2[col];
            }
        }
    }
}

// ---- final: out = log_softmax(T + B64) over 64 cols -------------------------
// wave = 4 rows; lane: row = lane>>4, 4 cols per lane (float4-contiguous).
__global__ __launch_bounds__(256) void k_lsm(const float* __restrict__ T,
                                             const ushort_t* __restrict__ B64,
                                             float* __restrict__ out, int n) {
    const int t = threadIdx.x;
    const int lane = t & 63;
    const int wv = blockIdx.x * 4 + (t >> 6);
    const int row = wv * 4 + (lane >> 4);
    const int cg = lane & 15;
    const bool ok = (row < n);
    float v[4];
    if (ok) {
        f32x4 tv = *(const f32x4*)&T[(size_t)row * 64 + cg * 4];
        ushort4v bv = *(const ushort4v*)&B64[(size_t)row * 64 + cg * 4];
#pragma unroll
        for (int j = 0; j < 4; ++j) v[j] = tv[j] + bf2f((ushort_t)bv[j]);
    } else {
#pragma unroll
        for (int j = 0; j < 4; ++j) v[j] = 0.f;
    }
    float m = fmaxf(fmaxf(v[0], v[1]), fmaxf(v[2], v[3]));
#pragma unroll
    for (int d = 1; d < 16; d <<= 1) m = fmaxf(m, __shfl_xor(m, d));
    float e = expf(v[0] - m) + expf(v[1] - m) + expf(v[2] - m) + expf(v[3] - m);
#pragma unroll
    for (int d = 1; d < 16; d <<= 1) e += __shfl_xor(e, d);
    float lg = m + logf(e);
    if (ok) {
        f32x4 o;
#pragma unroll
        for (int j = 0; j < 4; ++j) o[j] = v[j] - lg;
        *(f32x4*)&out[(size_t)row * 64 + cg * 4] = o;
    }
}

// ---- segment mean over CSR: 16 lanes/node (D=128) or 8 (D=64), 16B loads ---
template <int D>
__global__ __launch_bounds__(256) void k_segmean_bf(const ushort_t* __restrict__ U,
                                                    const int* __restrict__ off,
                                                    const int* __restrict__ srcs,
                                                    ushort_t* __restrict__ out,
                                                    int n) {
    constexpr int L = D / 8;       // lanes per node: 16 or 8
    constexpr int PER = 256 / L;   // nodes per block
    int node = blockIdx.x * PER + threadIdx.x / L;
    int sub = threadIdx.x % L;
    if (node >= n) return;
    int beg = off[node], end = off[node + 1];
    float a[8];
#pragma unroll
    for (int j = 0; j < 8; ++j) a[j] = 0.f;
    int i = beg;
    for (; i + 8 <= end; i += 8) {
        int sv[8];
#pragma unroll
        for (int u = 0; u < 8; ++u) sv[u] = srcs[i + u];
#pragma unroll
        for (int u = 0; u < 8; ++u) {
            ushort8 v = *(const ushort8*)&U[(size_t)sv[u] * D + sub * 8];
#pragma unroll
            for (int j = 0; j < 8; ++j) a[j] += bf2f((ushort_t)v[j]);
        }
    }
    for (; i + 4 <= end; i += 4) {
        int sv[4];
#pragma unroll
        for (int u = 0; u < 4; ++u) sv[u] = srcs[i + u];
#pragma unroll
        for (int u = 0; u < 4; ++u) {
            ushort8 v = *(const ushort8*)&U[(size_t)sv[u] * D + sub * 8];
#pragma unroll
            for (int j = 0; j < 8; ++j) a[j] += bf2f((ushort_t)v[j]);
        }
    }
    for (; i < end; ++i) {
        ushort8 v = *(const ushort8*)&U[(size_t)srcs[i] * D + sub * 8];
#pragma unroll
        for (int j = 0; j < 8; ++j) a[j] += bf2f((ushort_t)v[j]);
    }
    int d = end - beg;
    float inv = 1.f / (float)(d > 1 ? d : 1);
    ushort8 o;
#pragma unroll
    for (int j = 0; j < 8; ++j) o[j] = f2bf(a[j] * inv);
    *(ushort8*)&out[(size_t)node * D + sub * 8] = o;
}

// ---- BN apply + relu + residual(x f32), P bf16 -> H bf16 -------------------
__global__ __launch_bounds__(256) void k_bnapply(const ushort_t* __restrict__ P,
                                                 const float* __restrict__ X,
                                                 const float* __restrict__ stats,
                                                 const float* __restrict__ gamma,
                                                 const float* __restrict__ beta,
                                                 ushort_t* __restrict__ H, int n) {
    int i = blockIdx.x * 256 + threadIdx.x;  // one thread = 2 channels
    if (i >= n * 64) return;
    int nd = i >> 6;
    int c = (i & 63) << 1;
    float inv_n = 1.f / (float)n;
    float mu0 = stats[c] * inv_n, mu1 = stats[c + 1] * inv_n;
    float v0 = stats[128 + c] * inv_n - mu0 * mu0;
    float v1 = stats[128 + c + 1] * inv_n - mu1 * mu1;
    float s0 = rsqrtf(v0 + WS_EPS) * gamma[c];
    float s1 = rsqrtf(v1 + WS_EPS) * gamma[c + 1];
    uint_t pv = *(const uint_t*)&P[(size_t)nd * 128 + c];
    float p0 = __uint_as_float(pv << 16);
    float p1 = __uint_as_float(pv & 0xffff0000u);
    float2 xr = *(const float2*)&X[(size_t)nd * 128 + c];
    float h0 = fmaxf((p0 - mu0) * s0 + beta[c], 0.f) + xr.x;
    float h1 = fmaxf((p1 - mu1) * s1 + beta[c + 1], 0.f) + xr.y;
    uint_t pk = (uint_t)f2bf(h0) | ((uint_t)f2bf(h1) << 16);
    *(uint_t*)&H[(size_t)nd * 128 + c] = pk;
}

// ---------------------------------------------------------------------------
extern "C" void kernel_launch(void* const* d_in, const int* in_sizes, int n_in,
                              void* d_out, int out_size, void* d_ws, size_t ws_size,
                              hipStream_t stream) {
    const float* x     = (const float*)d_in[0];
    const int*   ei    = (const int*)d_in[1];
    const float* Wl0   = (const float*)d_in[2];
    const float* Wr0   = (const float*)d_in[3];
    const float* b0    = (const float*)d_in[4];
    const float* Wl1   = (const float*)d_in[5];
    const float* Wr1   = (const float*)d_in[6];
    const float* b1    = (const float*)d_in[7];
    const float* Wl2   = (const float*)d_in[8];
    const float* Wr2   = (const float*)d_in[9];
    const float* b2    = (const float*)d_in[10];
    const float* gamma = (const float*)d_in[11];
    const float* beta  = (const float*)d_in[12];

    const int n = in_sizes[0] / 128;
    const int E = in_sizes[1] / 2;
    const int nb_scan = (n + SCHUNK - 1) / SCHUNK;

    char* w = (char*)d_ws;
    auto alloc = [&](size_t bytes) -> void* {
        void* p = (void*)w;
        w += (bytes + 255) & ~(size_t)255;
        return p;
    };
    int*      deg   = (int*)alloc((size_t)n * 4);
    int*      cur   = (int*)alloc((size_t)n * 4);
    float*    stats = (float*)alloc(256 * 4);
    size_t    zbytes = (size_t)((char*)w - (char*)deg);
    int*      off   = (int*)alloc(((size_t)n + 1) * 4);
    int*      csr   = (int*)alloc((size_t)E * 4);
    int*      bsum  = (int*)alloc(256 * 4);
    int*      boff  = (int*)alloc(256 * 4);
    ushort_t* wts   = (ushort_t*)alloc((size_t)81920 * 2);
    ushort_t* xb    = (ushort_t*)alloc((size_t)n * 128 * 2);
    ushort_t* H     = (ushort_t*)alloc((size_t)n * 128 * 2);
    ushort_t* Pb    = (ushort_t*)alloc((size_t)n * 128 * 2);
    ushort_t* slabB = (ushort_t*)alloc((size_t)n * 128 * 2);
    float*    T     = (float*)alloc((size_t)n * 64 * 4);

    ushort_t* WtL0 = wts;
    ushort_t* WtR0 = wts + 16384;
    ushort_t* WtL1 = wts + 32768;
    ushort_t* WtR1 = wts + 49152;
    ushort_t* WtL2 = wts + 65536;
    ushort_t* WtR2 = wts + 73728;

    ushort_t* M   = slabB;
    ushort_t* A64 = slabB;
    ushort_t* B64 = slabB + (size_t)n * 64;

    hipMemsetAsync(deg, 0, zbytes, stream);

    const int eb = (E + 255) / 256;
    k_deg<<<eb, 256, 0, stream>>>(ei, deg, E);
    k_scan_part<<<nb_scan, 256, 0, stream>>>(deg, bsum, n);
    k_scan_bsum<<<1, 64, 0, stream>>>(bsum, boff, off + n, nb_scan);
    k_scan_apply<<<nb_scan, 256, 0, stream>>>(deg, boff, off, n);
    k_scatter<<<eb, 256, 0, stream>>>(ei, off, cur, csr, E);

    const int nb_cvt = (n * 64 + 255) / 256;
    k_prep<<<nb_cvt + 320, 256, 0, stream>>>(x, xb, n * 64, nb_cvt,
                                             Wl0, Wr0, Wl1, Wr1, Wl2, Wr2, wts);

    const int strips = (n + 15) / 16;
    const int gb2 = (strips * 2 + 3) / 4;     // 2 waves/strip, 4 waves/block
    const int smb128 = (n + 15) / 16;
    const int smb64 = (n + 31) / 32;
    const int lsb = (n + 15) / 16;

    // layer 0: M = segmean(xb); H = relu(xb@Wr0 + M@Wl0 + b0)
    k_segmean_bf<128><<<smb128, 256, 0, stream>>>(xb, off, csr, M, n);
    k_dgemm<2><<<gb2, 256, 0, stream>>>(xb, WtR0, M, WtL0, b0, H, nullptr, n);

    // layer 1: M = segmean(H); Pb = H@Wr1 + M@Wl1 + b1 (+BN stats);
    //          H = bf16(relu(BN(Pb)) + x)
    k_segmean_bf<128><<<smb128, 256, 0, stream>>>(H, off, csr, M, n);
    k_dgemm<1><<<gb2, 256, 0, stream>>>(H, WtR1, M, WtL1, b1, Pb, stats, n);
    k_bnapply<<<(n * 64 + 255) / 256, 256, 0, stream>>>(Pb, x, stats, gamma, beta, H, n);

    // layer 2: A64 = H@Wl2, T = H@Wr2 + b2 (one kernel); B64 = segmean(A64);
    //          out = log_softmax(T + B64)
    k_cgemm<<<gb2, 256, 0, stream>>>(H, WtL2, WtR2, b2, A64, T, n);
    k_segmean_bf<64><<<smb64, 256, 0, stream>>>(A64, off, csr, B64, n);
    k_lsm<<<lsb, 256, 0, stream>>>(T, B64, (float*)d_out, n);
}

// Round 8
// 234.064 us; speedup vs baseline: 1.2060x; 1.2060x over previous
//
#include <hip/hip_runtime.h>
#include <hip/hip_bf16.h>

// ---------------------------------------------------------------------------
// GraphSAGE 3-layer forward. bf16 MFMA GEMMs (f32 accum), bf16 activations.
// R8: anti-serialization GEMMs — B-fragments register-resident per wave
// (loaded once, batched), persistent waves grid-stride over 16-row strips,
// A-fragments batch-loaded with 1-strip register prefetch. No LDS/barriers.
// (R4-R7 all serialized VMEM: VGPR=52 forced one-load-per-MFMA round trips.)
//   layer0: H = relu(x@Wr0 + segmean(x)@Wl0 + b0)
//   layer1: Pb = H@Wr1 + segmean(H)@Wl1 + b1 (+f32 BN stats);
//           H = bf16(relu(BN(Pb)) + x)
//   layer2: {A64 = H@Wl2, T = H@Wr2 + b2}; B64 = segmean(A64);
//           out = log_softmax(T + B64)
// ---------------------------------------------------------------------------

#define WS_EPS 1e-5f

typedef unsigned short ushort_t;
typedef unsigned int uint_t;
typedef ushort_t ushort8 __attribute__((ext_vector_type(8)));
typedef ushort_t ushort4v __attribute__((ext_vector_type(4)));
typedef short short8 __attribute__((ext_vector_type(8)));
typedef float f32x4 __attribute__((ext_vector_type(4)));

__device__ __forceinline__ float bf2f(ushort_t u) {
    return __uint_as_float(((uint_t)u) << 16);
}
__device__ __forceinline__ ushort_t f2bf(float f) {
    uint_t u = __float_as_uint(f);
    u = (u + 0x7fffu + ((u >> 16) & 1u)) >> 16;  // RNE
    return (ushort_t)u;
}

// ---- CSR build -------------------------------------------------------------
__global__ __launch_bounds__(256) void k_deg(const int* __restrict__ ei,
                                             int* __restrict__ deg, int E) {
    int e = blockIdx.x * 256 + threadIdx.x;
    if (e < E) atomicAdd(&deg[ei[E + e]], 1);
}

constexpr int SCHUNK = 4096;

__global__ __launch_bounds__(256) void k_scan_part(const int* __restrict__ deg,
                                                   int* __restrict__ bsum, int n) {
    int t = threadIdx.x;
    int base = blockIdx.x * SCHUNK + t * 16;
    int s = 0;
#pragma unroll
    for (int j = 0; j < 16; ++j) {
        int i = base + j;
        if (i < n) s += deg[i];
    }
#pragma unroll
    for (int d = 1; d < 64; d <<= 1) s += __shfl_xor(s, d);
    __shared__ int wt[4];
    if ((t & 63) == 0) wt[t >> 6] = s;
    __syncthreads();
    if (t == 0) bsum[blockIdx.x] = wt[0] + wt[1] + wt[2] + wt[3];
}

__global__ __launch_bounds__(64) void k_scan_bsum(const int* __restrict__ bsum,
                                                  int* __restrict__ boff,
                                                  int* __restrict__ off_n, int nb) {
    int lane = threadIdx.x;
    int carry = 0;
    for (int base = 0; base < nb; base += 64) {
        int t = base + lane;
        int v = (t < nb) ? bsum[t] : 0;
        int x = v;
#pragma unroll
        for (int d = 1; d < 64; d <<= 1) {
            int y = __shfl_up(x, d);
            if (lane >= d) x += y;
        }
        if (t < nb) boff[t] = carry + x - v;
        carry += __shfl(x, 63);
    }
    if (lane == 0) *off_n = carry;
}

__global__ __launch_bounds__(256) void k_scan_apply(const int* __restrict__ deg,
                                                    const int* __restrict__ boff,
                                                    int* __restrict__ off, int n) {
    int t = threadIdx.x;
    int lane = t & 63, wid = t >> 6;
    int base = blockIdx.x * SCHUNK + t * 16;
    int v[16];
    int s = 0;
#pragma unroll
    for (int j = 0; j < 16; ++j) {
        int i = base + j;
        v[j] = (i < n) ? deg[i] : 0;
        s += v[j];
    }
    int x = s;
#pragma unroll
    for (int d = 1; d < 64; d <<= 1) {
        int y = __shfl_up(x, d);
        if (lane >= d) x += y;
    }
    __shared__ int wtot[4];
    if (lane == 63) wtot[wid] = x;
    __syncthreads();
    int woff = 0;
    for (int wj = 0; wj < wid; ++wj) woff += wtot[wj];
    int run = boff[blockIdx.x] + woff + x - s;
#pragma unroll
    for (int j = 0; j < 16; ++j) {
        int i = base + j;
        if (i < n) off[i] = run;
        run += v[j];
    }
}

__global__ __launch_bounds__(256) void k_scatter(const int* __restrict__ ei,
                                                 const int* __restrict__ off,
                                                 int* __restrict__ cur,
                                                 int* __restrict__ csr, int E) {
    int e = blockIdx.x * 256 + threadIdx.x;
    if (e < E) {
        int d = ei[E + e];
        int s = ei[e];
        int p = atomicAdd(&cur[d], 1);
        csr[off[d] + p] = s;
    }
}

// ---- prep: x -> bf16 AND weights -> bf16 transposed, one launch -------------
__global__ __launch_bounds__(256) void k_prep(const float* __restrict__ x,
                                              ushort_t* __restrict__ xb, int total2,
                                              int nb_cvt,
                                              const float* __restrict__ Wl0,
                                              const float* __restrict__ Wr0,
                                              const float* __restrict__ Wl1,
                                              const float* __restrict__ Wr1,
                                              const float* __restrict__ Wl2,
                                              const float* __restrict__ Wr2,
                                              ushort_t* __restrict__ wts) {
    int b = blockIdx.x;
    if (b < nb_cvt) {
        int i = b * 256 + threadIdx.x;
        if (i >= total2) return;
        float2 v = *(const float2*)&x[(size_t)i * 2];
        uint_t p = (uint_t)f2bf(v.x) | ((uint_t)f2bf(v.y) << 16);
        *(uint_t*)&xb[(size_t)i * 2] = p;
        return;
    }
    int id = (b - nb_cvt) * 256 + threadIdx.x;
    if (id >= 81920) return;
    const float* W;
    int rel, nout, base;
    if (id < 65536) {
        int m = id >> 14;
        rel = id & 16383;
        nout = 128;
        base = m << 14;
        W = (m == 0) ? Wl0 : (m == 1) ? Wr0 : (m == 2) ? Wl1 : Wr1;
    } else {
        int m = (id - 65536) >> 13;
        rel = (id - 65536) & 8191;
        nout = 64;
        base = 65536 + (m << 13);
        W = (m == 0) ? Wl2 : Wr2;
    }
    int c = rel >> 7;
    int k = rel & 127;
    wts[base + rel] = f2bf(W[(size_t)k * nout + c]);
}

// ---- persistent-wave dual GEMM: out = X1@W1 + X2@W2 + bias ------------------
// Wave: fixed 32-col quarter (cq), B-frags register-resident (16x short8),
// grid-stride over 16-row strips, A batch-loaded with 1-strip prefetch.
// EPI: 2 -> relu, bf16 out (layer 0); 1 -> bf16 out + f32 BN stats (layer 1).
template <int EPI>
__global__ __launch_bounds__(256, 3) void k_dgemm(const ushort_t* __restrict__ X1,
                                                  const ushort_t* __restrict__ W1,
                                                  const ushort_t* __restrict__ X2,
                                                  const ushort_t* __restrict__ W2,
                                                  const float* __restrict__ bias,
                                                  ushort_t* __restrict__ outp,
                                                  float* __restrict__ stats, int n) {
    constexpr int K = 128, NOUT = 128;
    const int t = threadIdx.x;
    const int lane = t & 63;
    const int r16 = lane & 15, kb = lane >> 4;
    const int gwv = blockIdx.x * 4 + (t >> 6);
    const int cq = gwv & 3;
    const int strips = (n + 15) >> 4;
    const int sstride = gridDim.x;  // nwaves/4

    const int col0 = cq * 32 + r16;          // fn=0 col for this lane
    // B-fragments: loaded once, batched (16 independent loads)
    short8 B1[2][4], B2[2][4];
#pragma unroll
    for (int fn = 0; fn < 2; ++fn)
#pragma unroll
        for (int ks = 0; ks < 4; ++ks)
            B1[fn][ks] = *(const short8*)&W1[(size_t)(col0 + fn * 16) * K + ks * 32 + kb * 8];
#pragma unroll
    for (int fn = 0; fn < 2; ++fn)
#pragma unroll
        for (int ks = 0; ks < 4; ++ks)
            B2[fn][ks] = *(const short8*)&W2[(size_t)(col0 + fn * 16) * K + ks * 32 + kb * 8];

    float bcol[2] = {bias[col0], bias[col0 + 16]};
    float ssum[2] = {0.f, 0.f}, qsum[2] = {0.f, 0.f};

    auto loadA = [&](short8* a, int s) {
        int arow = s * 16 + r16;
        bool ok = arow < n;
        size_t xo = (size_t)arow * K + kb * 8;
#pragma unroll
        for (int ks = 0; ks < 4; ++ks)
            a[ks] = ok ? *(const short8*)&X1[xo + ks * 32] : (short8)0;
#pragma unroll
        for (int ks = 0; ks < 4; ++ks)
            a[4 + ks] = ok ? *(const short8*)&X2[xo + ks * 32] : (short8)0;
    };

    auto work = [&](const short8* a, int s) {
        f32x4 acc0 = (f32x4)0.f, acc1 = (f32x4)0.f;
#pragma unroll
        for (int ks = 0; ks < 4; ++ks) {
            acc0 = __builtin_amdgcn_mfma_f32_16x16x32_bf16(a[ks], B1[0][ks], acc0, 0, 0, 0);
            acc1 = __builtin_amdgcn_mfma_f32_16x16x32_bf16(a[ks], B1[1][ks], acc1, 0, 0, 0);
        }
#pragma unroll
        for (int ks = 0; ks < 4; ++ks) {
            acc0 = __builtin_amdgcn_mfma_f32_16x16x32_bf16(a[4 + ks], B2[0][ks], acc0, 0, 0, 0);
            acc1 = __builtin_amdgcn_mfma_f32_16x16x32_bf16(a[4 + ks], B2[1][ks], acc1, 0, 0, 0);
        }
        int rb = s * 16 + kb * 4;
#pragma unroll
        for (int r = 0; r < 4; ++r) {
            int row = rb + r;
            if (row >= n) continue;
            float v0 = acc0[r] + bcol[0];
            float v1 = acc1[r] + bcol[1];
            if constexpr (EPI == 2) {
                outp[(size_t)row * NOUT + col0] = f2bf(fmaxf(v0, 0.f));
                outp[(size_t)row * NOUT + col0 + 16] = f2bf(fmaxf(v1, 0.f));
            } else {
                outp[(size_t)row * NOUT + col0] = f2bf(v0);
                outp[(size_t)row * NOUT + col0 + 16] = f2bf(v1);
                ssum[0] += v0; qsum[0] += v0 * v0;
                ssum[1] += v1; qsum[1] += v1 * v1;
            }
        }
    };

    short8 aA[8], aB[8];
    int s = gwv >> 2;
    if (s < strips) {
        loadA(aA, s);
        for (;;) {
            int s1 = s + sstride;
            bool v1 = (s1 < strips);
            if (v1) loadA(aB, s1);
            work(aA, s);
            if (!v1) break;
            int s2 = s1 + sstride;
            bool v2 = (s2 < strips);
            if (v2) loadA(aA, s2);
            work(aB, s1);
            if (!v2) break;
            s = s2;
        }
    }

    if constexpr (EPI == 1) {
#pragma unroll
        for (int fn = 0; fn < 2; ++fn) {
            ssum[fn] += __shfl_xor(ssum[fn], 16);
            ssum[fn] += __shfl_xor(ssum[fn], 32);
            qsum[fn] += __shfl_xor(qsum[fn], 16);
            qsum[fn] += __shfl_xor(qsum[fn], 32);
        }
        if (kb == 0) {
#pragma unroll
            for (int fn = 0; fn < 2; ++fn) {
                atomicAdd(&stats[col0 + fn * 16], ssum[fn]);
                atomicAdd(&stats[128 + col0 + fn * 16], qsum[fn]);
            }
        }
    }
}

// ---- persistent-wave layer-2 GEMM: A64 = H@Wl2 (bf16), T = H@Wr2+b2 (f32) --
// Wave: fixed 32-col half (hf), BOTH matrices' B-frags resident (16x short8),
// 4 A-loads feed 16 MFMAs per strip.
__global__ __launch_bounds__(256, 3) void k_cgemm(const ushort_t* __restrict__ H,
                                                  const ushort_t* __restrict__ WL,
                                                  const ushort_t* __restrict__ WR,
                                                  const float* __restrict__ b2,
                                                  ushort_t* __restrict__ A64,
                                                  float* __restrict__ T, int n) {
    constexpr int K = 128;
    const int t = threadIdx.x;
    const int lane = t & 63;
    const int r16 = lane & 15, kb = lane >> 4;
    const int gwv = blockIdx.x * 4 + (t >> 6);
    const int hf = gwv & 1;
    const int strips = (n + 15) >> 4;
    const int sstride = gridDim.x * 2;  // nwaves/2

    const int col0 = hf * 32 + r16;
    short8 BL[2][4], BR[2][4];
#pragma unroll
    for (int fn = 0; fn < 2; ++fn)
#pragma unroll
        for (int ks = 0; ks < 4; ++ks)
            BL[fn][ks] = *(const short8*)&WL[(size_t)(col0 + fn * 16) * K + ks * 32 + kb * 8];
#pragma unroll
    for (int fn = 0; fn < 2; ++fn)
#pragma unroll
        for (int ks = 0; ks < 4; ++ks)
            BR[fn][ks] = *(const short8*)&WR[(size_t)(col0 + fn * 16) * K + ks * 32 + kb * 8];

    float bcol[2] = {b2[col0], b2[col0 + 16]};

    auto loadA = [&](short8* a, int s) {
        int arow = s * 16 + r16;
        bool ok = arow < n;
        size_t xo = (size_t)arow * K + kb * 8;
#pragma unroll
        for (int ks = 0; ks < 4; ++ks)
            a[ks] = ok ? *(const short8*)&H[xo + ks * 32] : (short8)0;
    };

    auto work = [&](const short8* a, int s) {
        f32x4 al0 = (f32x4)0.f, al1 = (f32x4)0.f;
        f32x4 ar0 = (f32x4)0.f, ar1 = (f32x4)0.f;
#pragma unroll
        for (int ks = 0; ks < 4; ++ks) {
            al0 = __builtin_amdgcn_mfma_f32_16x16x32_bf16(a[ks], BL[0][ks], al0, 0, 0, 0);
            al1 = __builtin_amdgcn_mfma_f32_16x16x32_bf16(a[ks], BL[1][ks], al1, 0, 0, 0);
            ar0 = __builtin_amdgcn_mfma_f32_16x16x32_bf16(a[ks], BR[0][ks], ar0, 0, 0, 0);
            ar1 = __builtin_amdgcn_mfma_f32_16x16x32_bf16(a[ks], BR[1][ks], ar1, 0, 0, 0);
        }
        int rb = s * 16 + kb * 4;
#pragma unroll
        for (int r = 0; r < 4; ++r) {
            int row = rb + r;
            if (row >= n) continue;
            A64[(size_t)row * 64 + col0] = f2bf(al0[r]);
            A64[(size_t)row * 64 + col0 + 16] = f2bf(al1[r]);
            T[(size_t)row * 64 + col0] = ar0[r] + bcol[0];
            T[(size_t)row * 64 + col0 + 16] = ar1[r] + bcol[1];
        }
    };

    short8 aA[4], aB[4];
    int s = gwv >> 1;
    if (s < strips) {
        loadA(aA, s);
        for (;;) {
            int s1 = s + sstride;
            bool v1 = (s1 < strips);
            if (v1) loadA(aB, s1);
            work(aA, s);
            if (!v1) break;
            int s2 = s1 + sstride;
            bool v2 = (s2 < strips);
            if (v2) loadA(aA, s2);
            work(aB, s1);
            if (!v2) break;
            s = s2;
        }
    }
}

// ---- final: out = log_softmax(T + B64) over 64 cols -------------------------
__global__ __launch_bounds__(256) void k_lsm(const float* __restrict__ T,
                                             const ushort_t* __restrict__ B64,
                                             float* __restrict__ out, int n) {
    const int t = threadIdx.x;
    const int lane = t & 63;
    const int wv = blockIdx.x * 4 + (t >> 6);
    const int row = wv * 4 + (lane >> 4);
    const int cg = lane & 15;
    const bool ok = (row < n);
    float v[4];
    if (ok) {
        f32x4 tv = *(const f32x4*)&T[(size_t)row * 64 + cg * 4];
        ushort4v bv = *(const ushort4v*)&B64[(size_t)row * 64 + cg * 4];
#pragma unroll
        for (int j = 0; j < 4; ++j) v[j] = tv[j] + bf2f((ushort_t)bv[j]);
    } else {
#pragma unroll
        for (int j = 0; j < 4; ++j) v[j] = 0.f;
    }
    float m = fmaxf(fmaxf(v[0], v[1]), fmaxf(v[2], v[3]));
#pragma unroll
    for (int d = 1; d < 16; d <<= 1) m = fmaxf(m, __shfl_xor(m, d));
    float e = expf(v[0] - m) + expf(v[1] - m) + expf(v[2] - m) + expf(v[3] - m);
#pragma unroll
    for (int d = 1; d < 16; d <<= 1) e += __shfl_xor(e, d);
    float lg = m + logf(e);
    if (ok) {
        f32x4 o;
#pragma unroll
        for (int j = 0; j < 4; ++j) o[j] = v[j] - lg;
        *(f32x4*)&out[(size_t)row * 64 + cg * 4] = o;
    }
}

// ---- segment mean over CSR: 16 lanes/node (D=128) or 8 (D=64), 16B loads ---
template <int D>
__global__ __launch_bounds__(256) void k_segmean_bf(const ushort_t* __restrict__ U,
                                                    const int* __restrict__ off,
                                                    const int* __restrict__ srcs,
                                                    ushort_t* __restrict__ out,
                                                    int n) {
    constexpr int L = D / 8;       // lanes per node: 16 or 8
    constexpr int PER = 256 / L;   // nodes per block
    int node = blockIdx.x * PER + threadIdx.x / L;
    int sub = threadIdx.x % L;
    if (node >= n) return;
    int beg = off[node], end = off[node + 1];
    float a[8];
#pragma unroll
    for (int j = 0; j < 8; ++j) a[j] = 0.f;
    int i = beg;
    for (; i + 8 <= end; i += 8) {
        int sv[8];
#pragma unroll
        for (int u = 0; u < 8; ++u) sv[u] = srcs[i + u];
#pragma unroll
        for (int u = 0; u < 8; ++u) {
            ushort8 v = *(const ushort8*)&U[(size_t)sv[u] * D + sub * 8];
#pragma unroll
            for (int j = 0; j < 8; ++j) a[j] += bf2f((ushort_t)v[j]);
        }
    }
    for (; i + 4 <= end; i += 4) {
        int sv[4];
#pragma unroll
        for (int u = 0; u < 4; ++u) sv[u] = srcs[i + u];
#pragma unroll
        for (int u = 0; u < 4; ++u) {
            ushort8 v = *(const ushort8*)&U[(size_t)sv[u] * D + sub * 8];
#pragma unroll
            for (int j = 0; j < 8; ++j) a[j] += bf2f((ushort_t)v[j]);
        }
    }
    for (; i < end; ++i) {
        ushort8 v = *(const ushort8*)&U[(size_t)srcs[i] * D + sub * 8];
#pragma unroll
        for (int j = 0; j < 8; ++j) a[j] += bf2f((ushort_t)v[j]);
    }
    int d = end - beg;
    float inv = 1.f / (float)(d > 1 ? d : 1);
    ushort8 o;
#pragma unroll
    for (int j = 0; j < 8; ++j) o[j] = f2bf(a[j] * inv);
    *(ushort8*)&out[(size_t)node * D + sub * 8] = o;
}

// ---- BN apply + relu + residual(x f32), P bf16 -> H bf16 -------------------
__global__ __launch_bounds__(256) void k_bnapply(const ushort_t* __restrict__ P,
                                                 const float* __restrict__ X,
                                                 const float* __restrict__ stats,
                                                 const float* __restrict__ gamma,
                                                 const float* __restrict__ beta,
                                                 ushort_t* __restrict__ H, int n) {
    int i = blockIdx.x * 256 + threadIdx.x;  // one thread = 2 channels
    if (i >= n * 64) return;
    int nd = i >> 6;
    int c = (i & 63) << 1;
    float inv_n = 1.f / (float)n;
    float mu0 = stats[c] * inv_n, mu1 = stats[c + 1] * inv_n;
    float v0 = stats[128 + c] * inv_n - mu0 * mu0;
    float v1 = stats[128 + c + 1] * inv_n - mu1 * mu1;
    float s0 = rsqrtf(v0 + WS_EPS) * gamma[c];
    float s1 = rsqrtf(v1 + WS_EPS) * gamma[c + 1];
    uint_t pv = *(const uint_t*)&P[(size_t)nd * 128 + c];
    float p0 = __uint_as_float(pv << 16);
    float p1 = __uint_as_float(pv & 0xffff0000u);
    float2 xr = *(const float2*)&X[(size_t)nd * 128 + c];
    float h0 = fmaxf((p0 - mu0) * s0 + beta[c], 0.f) + xr.x;
    float h1 = fmaxf((p1 - mu1) * s1 + beta[c + 1], 0.f) + xr.y;
    uint_t pk = (uint_t)f2bf(h0) | ((uint_t)f2bf(h1) << 16);
    *(uint_t*)&H[(size_t)nd * 128 + c] = pk;
}

// ---------------------------------------------------------------------------
extern "C" void kernel_launch(void* const* d_in, const int* in_sizes, int n_in,
                              void* d_out, int out_size, void* d_ws, size_t ws_size,
                              hipStream_t stream) {
    const float* x     = (const float*)d_in[0];
    const int*   ei    = (const int*)d_in[1];
    const float* Wl0   = (const float*)d_in[2];
    const float* Wr0   = (const float*)d_in[3];
    const float* b0    = (const float*)d_in[4];
    const float* Wl1   = (const float*)d_in[5];
    const float* Wr1   = (const float*)d_in[6];
    const float* b1    = (const float*)d_in[7];
    const float* Wl2   = (const float*)d_in[8];
    const float* Wr2   = (const float*)d_in[9];
    const float* b2    = (const float*)d_in[10];
    const float* gamma = (const float*)d_in[11];
    const float* beta  = (const float*)d_in[12];

    const int n = in_sizes[0] / 128;
    const int E = in_sizes[1] / 2;
    const int nb_scan = (n + SCHUNK - 1) / SCHUNK;

    char* w = (char*)d_ws;
    auto alloc = [&](size_t bytes) -> void* {
        void* p = (void*)w;
        w += (bytes + 255) & ~(size_t)255;
        return p;
    };
    int*      deg   = (int*)alloc((size_t)n * 4);
    int*      cur   = (int*)alloc((size_t)n * 4);
    float*    stats = (float*)alloc(256 * 4);
    size_t    zbytes = (size_t)((char*)w - (char*)deg);
    int*      off   = (int*)alloc(((size_t)n + 1) * 4);
    int*      csr   = (int*)alloc((size_t)E * 4);
    int*      bsum  = (int*)alloc(256 * 4);
    int*      boff  = (int*)alloc(256 * 4);
    ushort_t* wts   = (ushort_t*)alloc((size_t)81920 * 2);
    ushort_t* xb    = (ushort_t*)alloc((size_t)n * 128 * 2);
    ushort_t* H     = (ushort_t*)alloc((size_t)n * 128 * 2);
    ushort_t* Pb    = (ushort_t*)alloc((size_t)n * 128 * 2);
    ushort_t* slabB = (ushort_t*)alloc((size_t)n * 128 * 2);
    float*    T     = (float*)alloc((size_t)n * 64 * 4);

    ushort_t* WtL0 = wts;
    ushort_t* WtR0 = wts + 16384;
    ushort_t* WtL1 = wts + 32768;
    ushort_t* WtR1 = wts + 49152;
    ushort_t* WtL2 = wts + 65536;
    ushort_t* WtR2 = wts + 73728;

    ushort_t* M   = slabB;
    ushort_t* A64 = slabB;
    ushort_t* B64 = slabB + (size_t)n * 64;

    hipMemsetAsync(deg, 0, zbytes, stream);

    const int eb = (E + 255) / 256;
    k_deg<<<eb, 256, 0, stream>>>(ei, deg, E);
    k_scan_part<<<nb_scan, 256, 0, stream>>>(deg, bsum, n);
    k_scan_bsum<<<1, 64, 0, stream>>>(bsum, boff, off + n, nb_scan);
    k_scan_apply<<<nb_scan, 256, 0, stream>>>(deg, boff, off, n);
    k_scatter<<<eb, 256, 0, stream>>>(ei, off, cur, csr, E);

    const int nb_cvt = (n * 64 + 255) / 256;
    k_prep<<<nb_cvt + 320, 256, 0, stream>>>(x, xb, n * 64, nb_cvt,
                                             Wl0, Wr0, Wl1, Wr1, Wl2, Wr2, wts);

    const int NB_G = 640;  // persistent-wave grid for GEMMs (2560 waves)
    const int smb128 = (n + 15) / 16;
    const int smb64 = (n + 31) / 32;
    const int lsb = (n + 15) / 16;

    // layer 0: M = segmean(xb); H = relu(xb@Wr0 + M@Wl0 + b0)
    k_segmean_bf<128><<<smb128, 256, 0, stream>>>(xb, off, csr, M, n);
    k_dgemm<2><<<NB_G, 256, 0, stream>>>(xb, WtR0, M, WtL0, b0, H, nullptr, n);

    // layer 1: M = segmean(H); Pb = H@Wr1 + M@Wl1 + b1 (+BN stats);
    //          H = bf16(relu(BN(Pb)) + x)
    k_segmean_bf<128><<<smb128, 256, 0, stream>>>(H, off, csr, M, n);
    k_dgemm<1><<<NB_G, 256, 0, stream>>>(H, WtR1, M, WtL1, b1, Pb, stats, n);
    k_bnapply<<<(n * 64 + 255) / 256, 256, 0, stream>>>(Pb, x, stats, gamma, beta, H, n);

    // layer 2: {A64 = H@Wl2, T = H@Wr2 + b2}; B64 = segmean(A64);
    //          out = log_softmax(T + B64)
    k_cgemm<<<NB_G, 256, 0, stream>>>(H, WtL2, WtR2, b2, A64, T, n);
    k_segmean_bf<64><<<smb64, 256, 0, stream>>>(A64, off, csr, B64, n);
    k_lsm<<<lsb, 256, 0, stream>>>(T, B64, (float*)d_out, n);
}

// Round 9
// 233.702 us; speedup vs baseline: 1.2079x; 1.0015x over previous
//
#include <hip/hip_runtime.h>
#include <hip/hip_bf16.h>

// ---------------------------------------------------------------------------
// GraphSAGE 3-layer forward. bf16 MFMA GEMMs (f32 accum), bf16 activations.
// R8: anti-serialization GEMMs — B-fragments register-resident per wave
// (loaded once, batched), persistent waves grid-stride over 16-row strips,
// A-fragments batch-loaded with 1-strip register prefetch. No LDS/barriers.
// (R4-R7 all serialized VMEM: VGPR=52 forced one-load-per-MFMA round trips.)
//   layer0: H = relu(x@Wr0 + segmean(x)@Wl0 + b0)
//   layer1: Pb = H@Wr1 + segmean(H)@Wl1 + b1 (+f32 BN stats);
//           H = bf16(relu(BN(Pb)) + x)
//   layer2: {A64 = H@Wl2, T = H@Wr2 + b2}; B64 = segmean(A64);
//           out = log_softmax(T + B64)
// ---------------------------------------------------------------------------

#define WS_EPS 1e-5f

typedef unsigned short ushort_t;
typedef unsigned int uint_t;
typedef ushort_t ushort8 __attribute__((ext_vector_type(8)));
typedef ushort_t ushort4v __attribute__((ext_vector_type(4)));
typedef short short8 __attribute__((ext_vector_type(8)));
typedef float f32x4 __attribute__((ext_vector_type(4)));

__device__ __forceinline__ float bf2f(ushort_t u) {
    return __uint_as_float(((uint_t)u) << 16);
}
__device__ __forceinline__ ushort_t f2bf(float f) {
    uint_t u = __float_as_uint(f);
    u = (u + 0x7fffu + ((u >> 16) & 1u)) >> 16;  // RNE
    return (ushort_t)u;
}

// ---- CSR build -------------------------------------------------------------
__global__ __launch_bounds__(256) void k_deg(const int* __restrict__ ei,
                                             int* __restrict__ deg, int E) {
    int e = blockIdx.x * 256 + threadIdx.x;
    if (e < E) atomicAdd(&deg[ei[E + e]], 1);
}

constexpr int SCHUNK = 4096;

__global__ __launch_bounds__(256) void k_scan_part(const int* __restrict__ deg,
                                                   int* __restrict__ bsum, int n) {
    int t = threadIdx.x;
    int base = blockIdx.x * SCHUNK + t * 16;
    int s = 0;
#pragma unroll
    for (int j = 0; j < 16; ++j) {
        int i = base + j;
        if (i < n) s += deg[i];
    }
#pragma unroll
    for (int d = 1; d < 64; d <<= 1) s += __shfl_xor(s, d);
    __shared__ int wt[4];
    if ((t & 63) == 0) wt[t >> 6] = s;
    __syncthreads();
    if (t == 0) bsum[blockIdx.x] = wt[0] + wt[1] + wt[2] + wt[3];
}

__global__ __launch_bounds__(64) void k_scan_bsum(const int* __restrict__ bsum,
                                                  int* __restrict__ boff,
                                                  int* __restrict__ off_n, int nb) {
    int lane = threadIdx.x;
    int carry = 0;
    for (int base = 0; base < nb; base += 64) {
        int t = base + lane;
        int v = (t < nb) ? bsum[t] : 0;
        int x = v;
#pragma unroll
        for (int d = 1; d < 64; d <<= 1) {
            int y = __shfl_up(x, d);
            if (lane >= d) x += y;
        }
        if (t < nb) boff[t] = carry + x - v;
        carry += __shfl(x, 63);
    }
    if (lane == 0) *off_n = carry;
}

__global__ __launch_bounds__(256) void k_scan_apply(const int* __restrict__ deg,
                                                    const int* __restrict__ boff,
                                                    int* __restrict__ off, int n) {
    int t = threadIdx.x;
    int lane = t & 63, wid = t >> 6;
    int base = blockIdx.x * SCHUNK + t * 16;
    int v[16];
    int s = 0;
#pragma unroll
    for (int j = 0; j < 16; ++j) {
        int i = base + j;
        v[j] = (i < n) ? deg[i] : 0;
        s += v[j];
    }
    int x = s;
#pragma unroll
    for (int d = 1; d < 64; d <<= 1) {
        int y = __shfl_up(x, d);
        if (lane >= d) x += y;
    }
    __shared__ int wtot[4];
    if (lane == 63) wtot[wid] = x;
    __syncthreads();
    int woff = 0;
    for (int wj = 0; wj < wid; ++wj) woff += wtot[wj];
    int run = boff[blockIdx.x] + woff + x - s;
#pragma unroll
    for (int j = 0; j < 16; ++j) {
        int i = base + j;
        if (i < n) off[i] = run;
        run += v[j];
    }
}

__global__ __launch_bounds__(256) void k_scatter(const int* __restrict__ ei,
                                                 const int* __restrict__ off,
                                                 int* __restrict__ cur,
                                                 int* __restrict__ csr, int E) {
    int e = blockIdx.x * 256 + threadIdx.x;
    if (e < E) {
        int d = ei[E + e];
        int s = ei[e];
        int p = atomicAdd(&cur[d], 1);
        csr[off[d] + p] = s;
    }
}

// ---- prep: x -> bf16 AND weights -> bf16 transposed, one launch -------------
__global__ __launch_bounds__(256) void k_prep(const float* __restrict__ x,
                                              ushort_t* __restrict__ xb, int total2,
                                              int nb_cvt,
                                              const float* __restrict__ Wl0,
                                              const float* __restrict__ Wr0,
                                              const float* __restrict__ Wl1,
                                              const float* __restrict__ Wr1,
                                              const float* __restrict__ Wl2,
                                              const float* __restrict__ Wr2,
                                              ushort_t* __restrict__ wts) {
    int b = blockIdx.x;
    if (b < nb_cvt) {
        int i = b * 256 + threadIdx.x;
        if (i >= total2) return;
        float2 v = *(const float2*)&x[(size_t)i * 2];
        uint_t p = (uint_t)f2bf(v.x) | ((uint_t)f2bf(v.y) << 16);
        *(uint_t*)&xb[(size_t)i * 2] = p;
        return;
    }
    int id = (b - nb_cvt) * 256 + threadIdx.x;
    if (id >= 81920) return;
    const float* W;
    int rel, nout, base;
    if (id < 65536) {
        int m = id >> 14;
        rel = id & 16383;
        nout = 128;
        base = m << 14;
        W = (m == 0) ? Wl0 : (m == 1) ? Wr0 : (m == 2) ? Wl1 : Wr1;
    } else {
        int m = (id - 65536) >> 13;
        rel = (id - 65536) & 8191;
        nout = 64;
        base = 65536 + (m << 13);
        W = (m == 0) ? Wl2 : Wr2;
    }
    int c = rel >> 7;
    int k = rel & 127;
    wts[base + rel] = f2bf(W[(size_t)k * nout + c]);
}

// ---- persistent-wave dual GEMM: out = X1@W1 + X2@W2 + bias ------------------
// Wave: fixed 32-col quarter (cq), B-frags register-resident (16x short8),
// grid-stride over 16-row strips, A batch-loaded with 1-strip prefetch.
// EPI: 2 -> relu, bf16 out (layer 0); 1 -> bf16 out + f32 BN stats (layer 1).
template <int EPI>
__global__ __launch_bounds__(256, 3) void k_dgemm(const ushort_t* __restrict__ X1,
                                                  const ushort_t* __restrict__ W1,
                                                  const ushort_t* __restrict__ X2,
                                                  const ushort_t* __restrict__ W2,
                                                  const float* __restrict__ bias,
                                                  ushort_t* __restrict__ outp,
                                                  float* __restrict__ stats, int n) {
    constexpr int K = 128, NOUT = 128;
    const int t = threadIdx.x;
    const int lane = t & 63;
    const int r16 = lane & 15, kb = lane >> 4;
    const int gwv = blockIdx.x * 4 + (t >> 6);
    const int cq = gwv & 3;
    const int strips = (n + 15) >> 4;
    const int sstride = gridDim.x;  // nwaves/4

    const int col0 = cq * 32 + r16;          // fn=0 col for this lane
    // B-fragments: loaded once, batched (16 independent loads)
    short8 B1[2][4], B2[2][4];
#pragma unroll
    for (int fn = 0; fn < 2; ++fn)
#pragma unroll
        for (int ks = 0; ks < 4; ++ks)
            B1[fn][ks] = *(const short8*)&W1[(size_t)(col0 + fn * 16) * K + ks * 32 + kb * 8];
#pragma unroll
    for (int fn = 0; fn < 2; ++fn)
#pragma unroll
        for (int ks = 0; ks < 4; ++ks)
            B2[fn][ks] = *(const short8*)&W2[(size_t)(col0 + fn * 16) * K + ks * 32 + kb * 8];

    float bcol[2] = {bias[col0], bias[col0 + 16]};
    float ssum[2] = {0.f, 0.f}, qsum[2] = {0.f, 0.f};

    auto loadA = [&](short8* a, int s) {
        int arow = s * 16 + r16;
        bool ok = arow < n;
        size_t xo = (size_t)arow * K + kb * 8;
#pragma unroll
        for (int ks = 0; ks < 4; ++ks)
            a[ks] = ok ? *(const short8*)&X1[xo + ks * 32] : (short8)0;
#pragma unroll
        for (int ks = 0; ks < 4; ++ks)
            a[4 + ks] = ok ? *(const short8*)&X2[xo + ks * 32] : (short8)0;
    };

    auto work = [&](const short8* a, int s) {
        f32x4 acc0 = (f32x4)0.f, acc1 = (f32x4)0.f;
#pragma unroll
        for (int ks = 0; ks < 4; ++ks) {
            acc0 = __builtin_amdgcn_mfma_f32_16x16x32_bf16(a[ks], B1[0][ks], acc0, 0, 0, 0);
            acc1 = __builtin_amdgcn_mfma_f32_16x16x32_bf16(a[ks], B1[1][ks], acc1, 0, 0, 0);
        }
#pragma unroll
        for (int ks = 0; ks < 4; ++ks) {
            acc0 = __builtin_amdgcn_mfma_f32_16x16x32_bf16(a[4 + ks], B2[0][ks], acc0, 0, 0, 0);
            acc1 = __builtin_amdgcn_mfma_f32_16x16x32_bf16(a[4 + ks], B2[1][ks], acc1, 0, 0, 0);
        }
        int rb = s * 16 + kb * 4;
#pragma unroll
        for (int r = 0; r < 4; ++r) {
            int row = rb + r;
            if (row >= n) continue;
            float v0 = acc0[r] + bcol[0];
            float v1 = acc1[r] + bcol[1];
            if constexpr (EPI == 2) {
                outp[(size_t)row * NOUT + col0] = f2bf(fmaxf(v0, 0.f));
                outp[(size_t)row * NOUT + col0 + 16] = f2bf(fmaxf(v1, 0.f));
            } else {
                outp[(size_t)row * NOUT + col0] = f2bf(v0);
                outp[(size_t)row * NOUT + col0 + 16] = f2bf(v1);
                ssum[0] += v0; qsum[0] += v0 * v0;
                ssum[1] += v1; qsum[1] += v1 * v1;
            }
        }
    };

    short8 aA[8], aB[8];
    int s = gwv >> 2;
    if (s < strips) {
        loadA(aA, s);
        for (;;) {
            int s1 = s + sstride;
            bool v1 = (s1 < strips);
            if (v1) loadA(aB, s1);
            work(aA, s);
            if (!v1) break;
            int s2 = s1 + sstride;
            bool v2 = (s2 < strips);
            if (v2) loadA(aA, s2);
            work(aB, s1);
            if (!v2) break;
            s = s2;
        }
    }

    if constexpr (EPI == 1) {
#pragma unroll
        for (int fn = 0; fn < 2; ++fn) {
            ssum[fn] += __shfl_xor(ssum[fn], 16);
            ssum[fn] += __shfl_xor(ssum[fn], 32);
            qsum[fn] += __shfl_xor(qsum[fn], 16);
            qsum[fn] += __shfl_xor(qsum[fn], 32);
        }
        if (kb == 0) {
#pragma unroll
            for (int fn = 0; fn < 2; ++fn) {
                atomicAdd(&stats[col0 + fn * 16], ssum[fn]);
                atomicAdd(&stats[128 + col0 + fn * 16], qsum[fn]);
            }
        }
    }
}

// ---- persistent-wave layer-2 GEMM: A64 = H@Wl2 (bf16), T = H@Wr2+b2 (f32) --
// Wave: fixed 32-col half (hf), BOTH matrices' B-frags resident (16x short8),
// 4 A-loads feed 16 MFMAs per strip.
__global__ __launch_bounds__(256, 3) void k_cgemm(const ushort_t* __restrict__ H,
                                                  const ushort_t* __restrict__ WL,
                                                  const ushort_t* __restrict__ WR,
                                                  const float* __restrict__ b2,
                                                  ushort_t* __restrict__ A64,
                                                  float* __restrict__ T, int n) {
    constexpr int K = 128;
    const int t = threadIdx.x;
    const int lane = t & 63;
    const int r16 = lane & 15, kb = lane >> 4;
    const int gwv = blockIdx.x * 4 + (t >> 6);
    const int hf = gwv & 1;
    const int strips = (n + 15) >> 4;
    const int sstride = gridDim.x * 2;  // nwaves/2

    const int col0 = hf * 32 + r16;
    short8 BL[2][4], BR[2][4];
#pragma unroll
    for (int fn = 0; fn < 2; ++fn)
#pragma unroll
        for (int ks = 0; ks < 4; ++ks)
            BL[fn][ks] = *(const short8*)&WL[(size_t)(col0 + fn * 16) * K + ks * 32 + kb * 8];
#pragma unroll
    for (int fn = 0; fn < 2; ++fn)
#pragma unroll
        for (int ks = 0; ks < 4; ++ks)
            BR[fn][ks] = *(const short8*)&WR[(size_t)(col0 + fn * 16) * K + ks * 32 + kb * 8];

    float bcol[2] = {b2[col0], b2[col0 + 16]};

    auto loadA = [&](short8* a, int s) {
        int arow = s * 16 + r16;
        bool ok = arow < n;
        size_t xo = (size_t)arow * K + kb * 8;
#pragma unroll
        for (int ks = 0; ks < 4; ++ks)
            a[ks] = ok ? *(const short8*)&H[xo + ks * 32] : (short8)0;
    };

    auto work = [&](const short8* a, int s) {
        f32x4 al0 = (f32x4)0.f, al1 = (f32x4)0.f;
        f32x4 ar0 = (f32x4)0.f, ar1 = (f32x4)0.f;
#pragma unroll
        for (int ks = 0; ks < 4; ++ks) {
            al0 = __builtin_amdgcn_mfma_f32_16x16x32_bf16(a[ks], BL[0][ks], al0, 0, 0, 0);
            al1 = __builtin_amdgcn_mfma_f32_16x16x32_bf16(a[ks], BL[1][ks], al1, 0, 0, 0);
            ar0 = __builtin_amdgcn_mfma_f32_16x16x32_bf16(a[ks], BR[0][ks], ar0, 0, 0, 0);
            ar1 = __builtin_amdgcn_mfma_f32_16x16x32_bf16(a[ks], BR[1][ks], ar1, 0, 0, 0);
        }
        int rb = s * 16 + kb * 4;
#pragma unroll
        for (int r = 0; r < 4; ++r) {
            int row = rb + r;
            if (row >= n) continue;
            A64[(size_t)row * 64 + col0] = f2bf(al0[r]);
            A64[(size_t)row * 64 + col0 + 16] = f2bf(al1[r]);
            T[(size_t)row * 64 + col0] = ar0[r] + bcol[0];
            T[(size_t)row * 64 + col0 + 16] = ar1[r] + bcol[1];
        }
    };

    short8 aA[4], aB[4];
    int s = gwv >> 1;
    if (s < strips) {
        loadA(aA, s);
        for (;;) {
            int s1 = s + sstride;
            bool v1 = (s1 < strips);
            if (v1) loadA(aB, s1);
            work(aA, s);
            if (!v1) break;
            int s2 = s1 + sstride;
            bool v2 = (s2 < strips);
            if (v2) loadA(aA, s2);
            work(aB, s1);
            if (!v2) break;
            s = s2;
        }
    }
}

// ---- final: out = log_softmax(T + B64) over 64 cols -------------------------
__global__ __launch_bounds__(256) void k_lsm(const float* __restrict__ T,
                                             const ushort_t* __restrict__ B64,
                                             float* __restrict__ out, int n) {
    const int t = threadIdx.x;
    const int lane = t & 63;
    const int wv = blockIdx.x * 4 + (t >> 6);
    const int row = wv * 4 + (lane >> 4);
    const int cg = lane & 15;
    const bool ok = (row < n);
    float v[4];
    if (ok) {
        f32x4 tv = *(const f32x4*)&T[(size_t)row * 64 + cg * 4];
        ushort4v bv = *(const ushort4v*)&B64[(size_t)row * 64 + cg * 4];
#pragma unroll
        for (int j = 0; j < 4; ++j) v[j] = tv[j] + bf2f((ushort_t)bv[j]);
    } else {
#pragma unroll
        for (int j = 0; j < 4; ++j) v[j] = 0.f;
    }
    float m = fmaxf(fmaxf(v[0], v[1]), fmaxf(v[2], v[3]));
#pragma unroll
    for (int d = 1; d < 16; d <<= 1) m = fmaxf(m, __shfl_xor(m, d));
    float e = expf(v[0] - m) + expf(v[1] - m) + expf(v[2] - m) + expf(v[3] - m);
#pragma unroll
    for (int d = 1; d < 16; d <<= 1) e += __shfl_xor(e, d);
    float lg = m + logf(e);
    if (ok) {
        f32x4 o;
#pragma unroll
        for (int j = 0; j < 4; ++j) o[j] = v[j] - lg;
        *(f32x4*)&out[(size_t)row * 64 + cg * 4] = o;
    }
}

// ---- segment mean over CSR: 16 lanes/node (D=128) or 8 (D=64), 16B loads ---
template <int D>
__global__ __launch_bounds__(256) void k_segmean_bf(const ushort_t* __restrict__ U,
                                                    const int* __restrict__ off,
                                                    const int* __restrict__ srcs,
                                                    ushort_t* __restrict__ out,
                                                    int n) {
    constexpr int L = D / 8;       // lanes per node: 16 or 8
    constexpr int PER = 256 / L;   // nodes per block
    int node = blockIdx.x * PER + threadIdx.x / L;
    int sub = threadIdx.x % L;
    if (node >= n) return;
    int beg = off[node], end = off[node + 1];
    float a[8];
#pragma unroll
    for (int j = 0; j < 8; ++j) a[j] = 0.f;
    int i = beg;
    for (; i + 8 <= end; i += 8) {
        int sv[8];
#pragma unroll
        for (int u = 0; u < 8; ++u) sv[u] = srcs[i + u];
#pragma unroll
        for (int u = 0; u < 8; ++u) {
            ushort8 v = *(const ushort8*)&U[(size_t)sv[u] * D + sub * 8];
#pragma unroll
            for (int j = 0; j < 8; ++j) a[j] += bf2f((ushort_t)v[j]);
        }
    }
    for (; i + 4 <= end; i += 4) {
        int sv[4];
#pragma unroll
        for (int u = 0; u < 4; ++u) sv[u] = srcs[i + u];
#pragma unroll
        for (int u = 0; u < 4; ++u) {
            ushort8 v = *(const ushort8*)&U[(size_t)sv[u] * D + sub * 8];
#pragma unroll
            for (int j = 0; j < 8; ++j) a[j] += bf2f((ushort_t)v[j]);
        }
    }
    for (; i < end; ++i) {
        ushort8 v = *(const ushort8*)&U[(size_t)srcs[i] * D + sub * 8];
#pragma unroll
        for (int j = 0; j < 8; ++j) a[j] += bf2f((ushort_t)v[j]);
    }
    int d = end - beg;
    float inv = 1.f / (float)(d > 1 ? d : 1);
    ushort8 o;
#pragma unroll
    for (int j = 0; j < 8; ++j) o[j] = f2bf(a[j] * inv);
    *(ushort8*)&out[(size_t)node * D + sub * 8] = o;
}

// ---- BN apply + relu + residual(x f32), P bf16 -> H bf16 -------------------
__global__ __launch_bounds__(256) void k_bnapply(const ushort_t* __restrict__ P,
                                                 const float* __restrict__ X,
                                                 const float* __restrict__ stats,
                                                 const float* __restrict__ gamma,
                                                 const float* __restrict__ beta,
                                                 ushort_t* __restrict__ H, int n) {
    int i = blockIdx.x * 256 + threadIdx.x;  // one thread = 2 channels
    if (i >= n * 64) return;
    int nd = i >> 6;
    int c = (i & 63) << 1;
    float inv_n = 1.f / (float)n;
    float mu0 = stats[c] * inv_n, mu1 = stats[c + 1] * inv_n;
    float v0 = stats[128 + c] * inv_n - mu0 * mu0;
    float v1 = stats[128 + c + 1] * inv_n - mu1 * mu1;
    float s0 = rsqrtf(v0 + WS_EPS) * gamma[c];
    float s1 = rsqrtf(v1 + WS_EPS) * gamma[c + 1];
    uint_t pv = *(const uint_t*)&P[(size_t)nd * 128 + c];
    float p0 = __uint_as_float(pv << 16);
    float p1 = __uint_as_float(pv & 0xffff0000u);
    float2 xr = *(const float2*)&X[(size_t)nd * 128 + c];
    float h0 = fmaxf((p0 - mu0) * s0 + beta[c], 0.f) + xr.x;
    float h1 = fmaxf((p1 - mu1) * s1 + beta[c + 1], 0.f) + xr.y;
    uint_t pk = (uint_t)f2bf(h0) | ((uint_t)f2bf(h1) << 16);
    *(uint_t*)&H[(size_t)nd * 128 + c] = pk;
}

// ---------------------------------------------------------------------------
extern "C" void kernel_launch(void* const* d_in, const int* in_sizes, int n_in,
                              void* d_out, int out_size, void* d_ws, size_t ws_size,
                              hipStream_t stream) {
    const float* x     = (const float*)d_in[0];
    const int*   ei    = (const int*)d_in[1];
    const float* Wl0   = (const float*)d_in[2];
    const float* Wr0   = (const float*)d_in[3];
    const float* b0    = (const float*)d_in[4];
    const float* Wl1   = (const float*)d_in[5];
    const float* Wr1   = (const float*)d_in[6];
    const float* b1    = (const float*)d_in[7];
    const float* Wl2   = (const float*)d_in[8];
    const float* Wr2   = (const float*)d_in[9];
    const float* b2    = (const float*)d_in[10];
    const float* gamma = (const float*)d_in[11];
    const float* beta  = (const float*)d_in[12];

    const int n = in_sizes[0] / 128;
    const int E = in_sizes[1] / 2;
    const int nb_scan = (n + SCHUNK - 1) / SCHUNK;

    char* w = (char*)d_ws;
    auto alloc = [&](size_t bytes) -> void* {
        void* p = (void*)w;
        w += (bytes + 255) & ~(size_t)255;
        return p;
    };
    int*      deg   = (int*)alloc((size_t)n * 4);
    int*      cur   = (int*)alloc((size_t)n * 4);
    float*    stats = (float*)alloc(256 * 4);
    size_t    zbytes = (size_t)((char*)w - (char*)deg);
    int*      off   = (int*)alloc(((size_t)n + 1) * 4);
    int*      csr   = (int*)alloc((size_t)E * 4);
    int*      bsum  = (int*)alloc(256 * 4);
    int*      boff  = (int*)alloc(256 * 4);
    ushort_t* wts   = (ushort_t*)alloc((size_t)81920 * 2);
    ushort_t* xb    = (ushort_t*)alloc((size_t)n * 128 * 2);
    ushort_t* H     = (ushort_t*)alloc((size_t)n * 128 * 2);
    ushort_t* Pb    = (ushort_t*)alloc((size_t)n * 128 * 2);
    ushort_t* slabB = (ushort_t*)alloc((size_t)n * 128 * 2);
    float*    T     = (float*)alloc((size_t)n * 64 * 4);

    ushort_t* WtL0 = wts;
    ushort_t* WtR0 = wts + 16384;
    ushort_t* WtL1 = wts + 32768;
    ushort_t* WtR1 = wts + 49152;
    ushort_t* WtL2 = wts + 65536;
    ushort_t* WtR2 = wts + 73728;

    ushort_t* M   = slabB;
    ushort_t* A64 = slabB;
    ushort_t* B64 = slabB + (size_t)n * 64;

    hipMemsetAsync(deg, 0, zbytes, stream);

    const int eb = (E + 255) / 256;
    k_deg<<<eb, 256, 0, stream>>>(ei, deg, E);
    k_scan_part<<<nb_scan, 256, 0, stream>>>(deg, bsum, n);
    k_scan_bsum<<<1, 64, 0, stream>>>(bsum, boff, off + n, nb_scan);
    k_scan_apply<<<nb_scan, 256, 0, stream>>>(deg, boff, off, n);
    k_scatter<<<eb, 256, 0, stream>>>(ei, off, cur, csr, E);

    const int nb_cvt = (n * 64 + 255) / 256;
    k_prep<<<nb_cvt + 320, 256, 0, stream>>>(x, xb, n * 64, nb_cvt,
                                             Wl0, Wr0, Wl1, Wr1, Wl2, Wr2, wts);

    const int NB_G = 640;  // persistent-wave grid for GEMMs (2560 waves)
    const int smb128 = (n + 15) / 16;
    const int smb64 = (n + 31) / 32;
    const int lsb = (n + 15) / 16;

    // layer 0: M = segmean(xb); H = relu(xb@Wr0 + M@Wl0 + b0)
    k_segmean_bf<128><<<smb128, 256, 0, stream>>>(xb, off, csr, M, n);
    k_dgemm<2><<<NB_G, 256, 0, stream>>>(xb, WtR0, M, WtL0, b0, H, nullptr, n);

    // layer 1: M = segmean(H); Pb = H@Wr1 + M@Wl1 + b1 (+BN stats);
    //          H = bf16(relu(BN(Pb)) + x)
    k_segmean_bf<128><<<smb128, 256, 0, stream>>>(H, off, csr, M, n);
    k_dgemm<1><<<NB_G, 256, 0, stream>>>(H, WtR1, M, WtL1, b1, Pb, stats, n);
    k_bnapply<<<(n * 64 + 255) / 256, 256, 0, stream>>>(Pb, x, stats, gamma, beta, H, n);

    // layer 2: {A64 = H@Wl2, T = H@Wr2 + b2}; B64 = segmean(A64);
    //          out = log_softmax(T + B64)
    k_cgemm<<<NB_G, 256, 0, stream>>>(H, WtL2, WtR2, b2, A64, T, n);
    k_segmean_bf<64><<<smb64, 256, 0, stream>>>(A64, off, csr, B64, n);
    k_lsm<<<lsb, 256, 0, stream>>>(T, B64, (float*)d_out, n);
}